// Round 7
// baseline (12437.970 us; speedup 1.0000x reference)
//
#include <hip/hip_runtime.h>
#include <math.h>

#define H    256
#define G4H  1024
#define CIN  512
#define BB   16
#define TT   2048
#define CHUNK 256
#define NPH  8   // TT/CHUNK

// ---- workspace layout (in floats) ----
#define OFF_PROJF   ((size_t)524288)                   // 256*16*1024
#define OFF_PROJB   (OFF_PROJF + (size_t)4194304)
#define OFF_HBUF    (OFF_PROJB + (size_t)4194304)      // 2048*16*512
#define OFF_STATS   (OFF_HBUF  + (size_t)16777216)     // 1024
#define OFF_HSTATE  (OFF_STATS + (size_t)1024)         // 2dir*16b*256 = 8192
#define OFF_CSTATE  (OFF_HSTATE + (size_t)8192)        // 8192
#define OFF_HX      (OFF_CSTATE + (size_t)8192)        // 2dir*2grp*2buf*2048 = 16384
#define OFF_FLAGS   (OFF_HX + (size_t)16384)           // 2dir*32wg*2grp*16 = 2048 (<4096)
#define OFF_W2      (OFF_FLAGS + (size_t)4096)         // 1024
#define OFF_B2      (OFF_W2 + (size_t)1024)            // 16
#define OFF_SAMP    (OFF_B2 + (size_t)16)              // 16*2048

// ---------------- K0: zero stats + epochs ----------------
__global__ __launch_bounds__(256) void k0_init(float* __restrict__ stats,
                                               int* __restrict__ flags) {
  int idx = blockIdx.x * 256 + threadIdx.x;
  if (idx < 1024) stats[idx] = 0.f;
  if (idx < 4096) flags[idx] = 0;   // epochs: zeroed ONCE; monotone absolute step counts
}

// ---------------- K1: proj[tc][b][g] = sum_c x[b][c][t] * Wih[g][c] + bih[g]+bhh[g] ----------------
__global__ __launch_bounds__(256) void k1_proj(
    const float* __restrict__ x,
    const float* __restrict__ WihF, const float* __restrict__ bihF, const float* __restrict__ bhhF,
    const float* __restrict__ WihB, const float* __restrict__ bihB, const float* __restrict__ bhhB,
    float* __restrict__ projF, float* __restrict__ projB, int t0f, int t0b) {
  __shared__ __align__(16) float Xs[16][68];
  __shared__ __align__(16) float Ws[16][68];
  int tid = threadIdx.x;
  int b = blockIdx.z & 15, dir = blockIdx.z >> 4;
  const float* Wih = dir ? WihB : WihF;
  const float* bih = dir ? bihB : bihF;
  const float* bhh = dir ? bhhB : bhhF;
  float* proj = dir ? projB : projF;
  int tbase = (dir ? t0b : t0f) + blockIdx.x * 64;
  int gbase = blockIdx.y * 64;
  int tx = tid & 15, ty = tid >> 4;
  float acc[4][4];
#pragma unroll
  for (int i = 0; i < 4; i++)
#pragma unroll
    for (int j = 0; j < 4; j++) acc[i][j] = 0.f;

  int lt = tid & 63, lk = tid >> 6;
  int wk = tid & 15, wg = tid >> 4;
  const float* xb = x + (size_t)b * CIN * TT;

  for (int c0 = 0; c0 < CIN; c0 += 16) {
    __syncthreads();
#pragma unroll
    for (int q = 0; q < 4; q++)
      Xs[lk + 4 * q][lt] = xb[(size_t)(c0 + lk + 4 * q) * TT + tbase + lt];
#pragma unroll
    for (int q = 0; q < 4; q++)
      Ws[wk][wg + 16 * q] = Wih[(size_t)(gbase + wg + 16 * q) * CIN + c0 + wk];
    __syncthreads();
#pragma unroll
    for (int kk = 0; kk < 16; kk++) {
      float4 av = *(const float4*)&Xs[kk][tx * 4];
      float4 bv = *(const float4*)&Ws[kk][ty * 4];
      acc[0][0] += av.x * bv.x; acc[0][1] += av.x * bv.y; acc[0][2] += av.x * bv.z; acc[0][3] += av.x * bv.w;
      acc[1][0] += av.y * bv.x; acc[1][1] += av.y * bv.y; acc[1][2] += av.y * bv.z; acc[1][3] += av.y * bv.w;
      acc[2][0] += av.z * bv.x; acc[2][1] += av.z * bv.y; acc[2][2] += av.z * bv.z; acc[2][3] += av.z * bv.w;
      acc[3][0] += av.w * bv.x; acc[3][1] += av.w * bv.y; acc[3][2] += av.w * bv.z; acc[3][3] += av.w * bv.w;
    }
  }
  int g0 = gbase + ty * 4;
  float bias0 = bih[g0 + 0] + bhh[g0 + 0];
  float bias1 = bih[g0 + 1] + bhh[g0 + 1];
  float bias2 = bih[g0 + 2] + bhh[g0 + 2];
  float bias3 = bih[g0 + 3] + bhh[g0 + 3];
#pragma unroll
  for (int i = 0; i < 4; i++) {
    int tc = blockIdx.x * 64 + tx * 4 + i;
    float4 st = make_float4(acc[i][0] + bias0, acc[i][1] + bias1,
                            acc[i][2] + bias2, acc[i][3] + bias3);
    *(float4*)(proj + ((size_t)tc * BB + b) * G4H + g0) = st;
  }
}

// ---------------- K2: batched LSTM recurrence ----------------
// 64 WGs: (dir, j-slice of 8). WG computes its 32 gate-rows for ALL 16 batches.
// Weights LDS-resident (32 rows x 256, pad 260). Thread: (kh,gate,j,b8).
// Streams: b-groups G0/G1; gate-masters wave0/wave1 run concurrently.
// Sync: relaxed agent atomics, per-(wg,group) padded epoch words, monotone targets.
__global__ __launch_bounds__(512, 1) void k2_rec(
    const float* __restrict__ WhhF, const float* __restrict__ WhhB,
    const float* __restrict__ projF, const float* __restrict__ projB,
    float* __restrict__ hbuf, float* __restrict__ hx, int* __restrict__ flags,
    float* __restrict__ hstate, float* __restrict__ cstate,
    float* __restrict__ stats, int t0f, int t0b, int first, int ebase) {
  __shared__ __align__(16) float wlds[32 * 260];
  __shared__ __align__(16) float hlds[16 * 260];
  __shared__ float pbuf0[512];
  __shared__ float pbuf1[512];

  const int tid = threadIdx.x;
  const int bx = blockIdx.x;
  const int dir = bx & 1, wg = bx >> 1;       // wg in [0,32)
  const int jbase = wg * 8;
  const int b = tid & 7, j = (tid >> 3) & 7, gate = (tid >> 6) & 3, kh = tid >> 8;
  const int wid = tid >> 6;                   // wave = kh*4+gate
  const int lane = tid & 63;                  // = j*8+b

  const float* Whh = dir ? WhhB : WhhF;
  const float* pbase = dir ? projB : projF;

  // stage weights: local row r = gate*8+jj  <- Whh[gate*256 + jbase + jj][:]
  for (int i = tid; i < 2048; i += 512) {     // 2048 float4s
    int r = i >> 6, cq = i & 63;
    int grow = (r >> 3) * 256 + jbase + (r & 7);
    float4 v = *(const float4*)(Whh + (size_t)grow * H + cq * 4);
    *(float4*)(wlds + r * 260 + cq * 4) = v;
  }
  // init h (16 b-rows x 256) and c
  for (int i = tid; i < 4096; i += 512) {
    int bg = i >> 8, jj = i & 255;
    hlds[bg * 260 + jj] = first ? 0.f : hstate[((dir * 16 + bg) << 8) + jj];
  }
  float cc = 0.f, s1 = 0.f, s2 = 0.f;
  if (wid < 2 && !first) cc = cstate[((dir * 16 + ((wid << 3) | b)) << 8) + jbase + j];
  __syncthreads();

  int* ebdir = flags + dir * 1024;            // 32 wg * 2 grp * 16
  float* hxd = hx + dir * 8192;               // 2 grp * 2 buf * 2048
  const int row = gate * 256 + jbase + j;

  float pv0 = 0.f, pv1 = 0.f;
  if (kh == 0) {
    int tc0 = dir ? (CHUNK - 1) : 0;
    const float* p = pbase + ((size_t)tc0 * BB + b) * G4H + row;
    pv0 = p[0];
    pv1 = p[(size_t)8 * G4H];
  }

  const float* wrow = wlds + (gate * 8 + j) * 260 + kh * 128;
  const float* h0p = hlds + b * 260 + kh * 128;
  const float* h1p = hlds + (8 + b) * 260 + kh * 128;

  for (int step = 0; step < CHUNK; ++step) {
    int tc = dir ? (CHUNK - 1 - step) : step;
    int t = (dir ? t0b : t0f) + tc;
    int target = ebase + step + 1;

    float a0 = (kh == 0) ? pv0 : 0.f;
    float a1 = (kh == 0) ? pv1 : 0.f;
#pragma unroll
    for (int q = 0; q < 32; ++q) {
      float4 wv = *(const float4*)(wrow + q * 4);
      float4 x0 = *(const float4*)(h0p + q * 4);
      float4 x1 = *(const float4*)(h1p + q * 4);
      a0 += wv.x * x0.x + wv.y * x0.y + wv.z * x0.z + wv.w * x0.w;
      a1 += wv.x * x1.x + wv.y * x1.y + wv.z * x1.z + wv.w * x1.w;
    }
    pbuf0[tid] = a0;
    pbuf1[tid] = a1;
    __syncthreads();                          // B1: pbufs ready, h_lds reads done

    if (wid < 2) {                            // wave0 -> G0, wave1 -> G1 (concurrent)
      const float* pb = wid ? pbuf1 : pbuf0;
      float gi = pb[lane]       + pb[256 + lane];
      float gf = pb[64 + lane]  + pb[320 + lane];
      float gg = pb[128 + lane] + pb[384 + lane];
      float go = pb[192 + lane] + pb[448 + lane];
      float ig = 1.f / (1.f + expf(-gi));
      float fg = 1.f / (1.f + expf(-gf));
      float gz = tanhf(gg);
      float og = 1.f / (1.f + expf(-go));
      cc = fg * cc + ig * gz;
      float h = og * tanhf(cc);
      s1 += h; s2 += h * h;
      __hip_atomic_store(&hxd[(wid * 2 + (step & 1)) * 2048 + b * 256 + jbase + j], h,
                         __ATOMIC_RELAXED, __HIP_MEMORY_SCOPE_AGENT);
      __asm__ volatile("s_waitcnt vmcnt(0) lgkmcnt(0)" ::: "memory");
      if (lane == 0)
        __hip_atomic_store(&ebdir[(wg * 2 + wid) * 16], target,
                           __ATOMIC_RELAXED, __HIP_MEMORY_SCOPE_AGENT);
      // streaming store off the critical path (after epoch publish)
      hbuf[((size_t)t * BB + ((wid << 3) | b)) * 512 + dir * 256 + jbase + j] = h;
    }
    if (kh == 0 && step + 1 < CHUNK) {        // prefetch next proj
      int tcn = dir ? (CHUNK - 2 - step) : (step + 1);
      const float* p = pbase + ((size_t)tcn * BB + b) * G4H + row;
      pv0 = p[0];
      pv1 = p[(size_t)8 * G4H];
    }
    __syncthreads();                          // B2: epochs published
    if (wid == 0) {
      for (;;) {
        int ep = target;
        if (lane < 32)
          ep = __hip_atomic_load(&ebdir[lane * 32], __ATOMIC_RELAXED, __HIP_MEMORY_SCOPE_AGENT);
        if (__all(ep >= target)) break;
      }
    } else if (wid == 1) {
      for (;;) {
        int ep = target;
        if (lane < 32)
          ep = __hip_atomic_load(&ebdir[lane * 32 + 16], __ATOMIC_RELAXED, __HIP_MEMORY_SCOPE_AGENT);
        if (__all(ep >= target)) break;
      }
    }
    __syncthreads();                          // B3: both groups complete
    for (int i = tid; i < 4096; i += 512) {   // reload full h (both groups)
      int bg = i >> 8, jj = i & 255;
      float v = __hip_atomic_load(
          &hxd[((bg >> 3) * 2 + (step & 1)) * 2048 + (bg & 7) * 256 + jj],
          __ATOMIC_RELAXED, __HIP_MEMORY_SCOPE_AGENT);
      hlds[bg * 260 + jj] = v;
    }
    __syncthreads();                          // B4: h ready for next step
  }

  for (int i = tid; i < 4096; i += 512) {
    int bg = i >> 8, jj = i & 255;
    hstate[((dir * 16 + bg) << 8) + jj] = hlds[bg * 260 + jj];
  }
  if (wid < 2) {
    cstate[((dir * 16 + ((wid << 3) | b)) << 8) + jbase + j] = cc;
    atomicAdd(&stats[dir * 256 + jbase + j], s1);
    atomicAdd(&stats[512 + dir * 256 + jbase + j], s2);
  }
}

// ---------------- K3: fold BN into linear ----------------
__global__ __launch_bounds__(512) void k3_prep(
    const float* __restrict__ stats, const float* __restrict__ gamma,
    const float* __restrict__ beta, const float* __restrict__ Wlin,
    const float* __restrict__ blin, float* __restrict__ w2, float* __restrict__ b2) {
  __shared__ float r0[512], r1[512];
  int ch = threadIdx.x;
  float mean = stats[ch] * (1.f / 32768.f);
  float var  = stats[512 + ch] * (1.f / 32768.f) - mean * mean;
  float sc = gamma[ch] * rsqrtf(var + 1e-5f);
  float w0 = Wlin[ch], w1 = Wlin[512 + ch];
  w2[ch] = w0 * sc; w2[512 + ch] = w1 * sc;
  float tt = beta[ch] - mean * sc;
  r0[ch] = w0 * tt; r1[ch] = w1 * tt;
  __syncthreads();
  for (int off = 256; off > 0; off >>= 1) {
    if (ch < off) { r0[ch] += r0[ch + off]; r1[ch] += r1[ch + off]; }
    __syncthreads();
  }
  if (ch == 0) { b2[0] = blin[0] + r0[0]; b2[1] = blin[1] + r1[0]; }
}

// ---------------- K4: posterior + gumbel hard sample; one wave per (b,t) ----------------
__global__ __launch_bounds__(256) void k4_post(
    const float* __restrict__ hbuf, const float* __restrict__ w2,
    const float* __restrict__ b2, const float* __restrict__ u,
    const float* __restrict__ e, float* __restrict__ post,
    float* __restrict__ samp) {
  int wid = (blockIdx.x * 256 + threadIdx.x) >> 6;
  int lane = threadIdx.x & 63;
  int b = wid >> 11, t = wid & 2047;
  const float* hr = hbuf + ((size_t)t * BB + b) * 512;
  int c0 = lane * 8;
  float d0 = 0.f, d1 = 0.f;
#pragma unroll
  for (int q = 0; q < 8; q++) {
    float hv = hr[c0 + q];
    d0 += w2[c0 + q] * hv;
    d1 += w2[512 + c0 + q] * hv;
  }
#pragma unroll
  for (int off = 32; off > 0; off >>= 1) {
    d0 += __shfl_xor(d0, off, 64);
    d1 += __shfl_xor(d1, off, 64);
  }
  if (lane == 0) {
    float z0 = (d0 + b2[0]) * 0.1f, z1 = (d1 + b2[1]) * 0.1f;
    float m = fmaxf(z0, z1);
    float e0 = expf(z0 - m), e1 = expf(z1 - m);
    float inv = 1.f / (e0 + e1);
    float p0 = e0 * inv, p1 = e1 * inv;
    size_t o = (size_t)b * TT + t;
    post[o * 2] = p0; post[o * 2 + 1] = p1;
    float u0 = u[o * 2], u1 = u[o * 2 + 1];
    float g0 = -logf(-logf(u0 + 1e-20f) + 1e-20f);
    float g1 = -logf(-logf(u1 + 1e-20f) + 1e-20f);
    float a0 = logf(p0) + g0, a1 = logf(p1) + g1;
    samp[o] = (a1 > a0) ? e[o] : 0.f;  // strict >: np.argmax tie -> class 0
  }
}

// ---------------- K5: 3x median-of-5 (reflect pad), one WG per b ----------------
#define MSWAP(a, b) { float lo_ = fminf(a, b); b = fmaxf(a, b); a = lo_; }
__global__ __launch_bounds__(256) void k5_median(
    const float* __restrict__ samp, float* __restrict__ mask) {
  __shared__ float buf[2][TT];
  int b = blockIdx.x, tid = threadIdx.x;
  for (int i = tid; i < TT; i += 256) buf[0][i] = samp[(size_t)b * TT + i];
  __syncthreads();
  int src = 0;
  for (int pass = 0; pass < 3; ++pass) {
    for (int i = tid; i < TT; i += 256) {
      float v0, v1, v2, v3, v4;
      {
        int i0 = i - 2; i0 = i0 < 0 ? -i0 : i0;
        int i1 = i - 1; i1 = i1 < 0 ? -i1 : i1;
        int i3 = i + 1; i3 = i3 > TT - 1 ? 2 * (TT - 1) - i3 : i3;
        int i4 = i + 2; i4 = i4 > TT - 1 ? 2 * (TT - 1) - i4 : i4;
        v0 = buf[src][i0]; v1 = buf[src][i1]; v2 = buf[src][i];
        v3 = buf[src][i3]; v4 = buf[src][i4];
      }
      MSWAP(v0, v1); MSWAP(v3, v4); MSWAP(v2, v4); MSWAP(v2, v3);
      MSWAP(v1, v4); MSWAP(v0, v3); MSWAP(v0, v2); MSWAP(v1, v3);
      MSWAP(v1, v2);
      buf[1 - src][i] = v2;
    }
    __syncthreads();
    src = 1 - src;
  }
  for (int i = tid; i < TT; i += 256) mask[(size_t)b * TT + i] = buf[src][i];
}

extern "C" void kernel_launch(void* const* d_in, const int* in_sizes, int n_in,
                              void* d_out, int out_size, void* d_ws, size_t ws_size,
                              hipStream_t stream) {
  const float* x    = (const float*)d_in[0];
  const float* e    = (const float*)d_in[1];
  const float* u    = (const float*)d_in[2];
  const float* WihF = (const float*)d_in[3];
  const float* WhhF = (const float*)d_in[4];
  const float* bihF = (const float*)d_in[5];
  const float* bhhF = (const float*)d_in[6];
  const float* WihB = (const float*)d_in[7];
  const float* WhhB = (const float*)d_in[8];
  const float* bihB = (const float*)d_in[9];
  const float* bhhB = (const float*)d_in[10];
  const float* gamma= (const float*)d_in[11];
  const float* beta = (const float*)d_in[12];
  const float* Wlin = (const float*)d_in[13];
  const float* blin = (const float*)d_in[14];

  float* ws = (float*)d_ws;
  float* projF  = ws + OFF_PROJF;
  float* projB  = ws + OFF_PROJB;
  float* hbuf   = ws + OFF_HBUF;
  float* stats  = ws + OFF_STATS;
  float* hstate = ws + OFF_HSTATE;
  float* cstate = ws + OFF_CSTATE;
  float* hx     = ws + OFF_HX;
  int*   flags  = (int*)(ws + OFF_FLAGS);
  float* w2     = ws + OFF_W2;
  float* b2     = ws + OFF_B2;
  float* samp   = ws + OFF_SAMP;

  float* post = (float*)d_out;
  float* mask = (float*)d_out + (size_t)BB * TT * 2;

  hipLaunchKernelGGL(k0_init, dim3(16), dim3(256), 0, stream, stats, flags);
  for (int p = 0; p < NPH; ++p) {
    int t0f = p * CHUNK;
    int t0b = (NPH - 1 - p) * CHUNK;
    hipLaunchKernelGGL(k1_proj, dim3(4, 16, 32), dim3(256), 0, stream,
                       x, WihF, bihF, bhhF, WihB, bihB, bhhB, projF, projB, t0f, t0b);
    hipLaunchKernelGGL(k2_rec, dim3(64), dim3(512), 0, stream,
                       WhhF, WhhB, projF, projB, hbuf, hx, flags,
                       hstate, cstate, stats, t0f, t0b, p == 0 ? 1 : 0, p * CHUNK);
  }
  hipLaunchKernelGGL(k3_prep, dim3(1), dim3(512), 0, stream,
                     stats, gamma, beta, Wlin, blin, w2, b2);
  hipLaunchKernelGGL(k4_post, dim3(8192), dim3(256), 0, stream,
                     hbuf, w2, b2, u, e, post, samp);
  hipLaunchKernelGGL(k5_median, dim3(16), dim3(256), 0, stream, samp, mask);
}

// Round 8
// 7973.900 us; speedup vs baseline: 1.5598x; 1.5598x over previous
//
#include <hip/hip_runtime.h>
#include <math.h>

#define H    256
#define G4H  1024
#define CIN  512
#define BB   16
#define TT   2048
#define CHUNK 256
#define NPH  8   // TT/CHUNK

// ---- workspace layout (in floats) ----
#define OFF_PROJF   ((size_t)0)                        // 256*16*1024 = 4194304
#define OFF_PROJB   ((size_t)4194304)
#define OFF_HBUF    ((size_t)8388608)                  // 2048*16*512 = 16777216
#define OFF_STATS   ((size_t)25165824)                 // 1024
#define OFF_CSTATE  ((size_t)25166848)                 // 8192
#define OFF_HX      ((size_t)25175040)                 // 16384 uint64 = 32768 floats (8B aligned)
#define OFF_W2      ((size_t)25207808)                 // 1024
#define OFF_B2      ((size_t)25208832)                 // 16
#define OFF_SAMP    ((size_t)25208848)                 // 16*2048

typedef unsigned long long ull;

// ---------------- K0: zero stats + hx tag words ----------------
__global__ __launch_bounds__(256) void k0_init(float* __restrict__ stats,
                                               int* __restrict__ hxw) {
  int idx = blockIdx.x * 256 + threadIdx.x;
  if (idx < 1024) stats[idx] = 0.f;
  if (idx < 32768) hxw[idx] = 0;   // tags=0 < any target>=1
}

// ---------------- K1: proj[tc][b][g] = sum_c x[b][c][t] * Wih[g][c] + bih[g]+bhh[g] ----------------
__global__ __launch_bounds__(256) void k1_proj(
    const float* __restrict__ x,
    const float* __restrict__ WihF, const float* __restrict__ bihF, const float* __restrict__ bhhF,
    const float* __restrict__ WihB, const float* __restrict__ bihB, const float* __restrict__ bhhB,
    float* __restrict__ projF, float* __restrict__ projB, int t0f, int t0b) {
  __shared__ __align__(16) float Xs[16][68];
  __shared__ __align__(16) float Ws[16][68];
  int tid = threadIdx.x;
  int b = blockIdx.z & 15, dir = blockIdx.z >> 4;
  const float* Wih = dir ? WihB : WihF;
  const float* bih = dir ? bihB : bihF;
  const float* bhh = dir ? bhhB : bhhF;
  float* proj = dir ? projB : projF;
  int tbase = (dir ? t0b : t0f) + blockIdx.x * 64;
  int gbase = blockIdx.y * 64;
  int tx = tid & 15, ty = tid >> 4;
  float acc[4][4];
#pragma unroll
  for (int i = 0; i < 4; i++)
#pragma unroll
    for (int j = 0; j < 4; j++) acc[i][j] = 0.f;

  int lt = tid & 63, lk = tid >> 6;
  int wk = tid & 15, wg = tid >> 4;
  const float* xb = x + (size_t)b * CIN * TT;

  for (int c0 = 0; c0 < CIN; c0 += 16) {
    __syncthreads();
#pragma unroll
    for (int q = 0; q < 4; q++)
      Xs[lk + 4 * q][lt] = xb[(size_t)(c0 + lk + 4 * q) * TT + tbase + lt];
#pragma unroll
    for (int q = 0; q < 4; q++)
      Ws[wk][wg + 16 * q] = Wih[(size_t)(gbase + wg + 16 * q) * CIN + c0 + wk];
    __syncthreads();
#pragma unroll
    for (int kk = 0; kk < 16; kk++) {
      float4 av = *(const float4*)&Xs[kk][tx * 4];
      float4 bv = *(const float4*)&Ws[kk][ty * 4];
      acc[0][0] += av.x * bv.x; acc[0][1] += av.x * bv.y; acc[0][2] += av.x * bv.z; acc[0][3] += av.x * bv.w;
      acc[1][0] += av.y * bv.x; acc[1][1] += av.y * bv.y; acc[1][2] += av.y * bv.z; acc[1][3] += av.y * bv.w;
      acc[2][0] += av.z * bv.x; acc[2][1] += av.z * bv.y; acc[2][2] += av.z * bv.z; acc[2][3] += av.z * bv.w;
      acc[3][0] += av.w * bv.x; acc[3][1] += av.w * bv.y; acc[3][2] += av.w * bv.z; acc[3][3] += av.w * bv.w;
    }
  }
  int g0 = gbase + ty * 4;
  float bias0 = bih[g0 + 0] + bhh[g0 + 0];
  float bias1 = bih[g0 + 1] + bhh[g0 + 1];
  float bias2 = bih[g0 + 2] + bhh[g0 + 2];
  float bias3 = bih[g0 + 3] + bhh[g0 + 3];
#pragma unroll
  for (int i = 0; i < 4; i++) {
    int tc = blockIdx.x * 64 + tx * 4 + i;
    float4 st = make_float4(acc[i][0] + bias0, acc[i][1] + bias1,
                            acc[i][2] + bias2, acc[i][3] + bias3);
    *(float4*)(proj + ((size_t)tc * BB + b) * G4H + g0) = st;
  }
}

// ---------------- K2: LSTM recurrence, tagged-word exchange ----------------
// 1024 WGs = 32 chains x 32 slices; WG: 256 thr, 32 gate-rows (4 gates x 8 j), weights in LDS.
// Thread: r = tid&31 (row), kc = tid>>5 (k-chunk of 32 cols).
// Exchange: hx2[parity][chain][j] = (tag=abs+1)<<32 | h_bits; consumers poll tag>=abs.
// 4 WG/CU co-residency REQUIRED (spin): launch_bounds(256,4) caps VGPR at 128.
__global__ __launch_bounds__(256, 4) void k2_rec(
    const float* __restrict__ WhhF, const float* __restrict__ WhhB,
    const float* __restrict__ projF, const float* __restrict__ projB,
    float* __restrict__ hbuf, ull* __restrict__ hx2,
    float* __restrict__ cstate, float* __restrict__ stats,
    int t0f, int t0b, int ebase, int first) {
  __shared__ __align__(16) float4 wq4[64 * 32];   // [q][row] 32 KB
  __shared__ __align__(16) float hlds[256];
  __shared__ float pbuf[256];                     // [kc][row]

  const int tid = threadIdx.x;
  const int r = tid & 31, kc = tid >> 5;
  const int gate = r >> 3, jj = r & 7;
  const int bx = blockIdx.x;
  const int grp = bx & 31, s = bx >> 5;           // chain, slice in [0,32)
  const int dir = grp >> 4, b = grp & 15;
  const int jb = s * 8;
  const int row = gate * 256 + jb + jj;

  const float* Whh = dir ? WhhB : WhhF;
  const float* pbase = dir ? projB : projF;

  // stage weights: wq4[q*32 + rr] = Whh[grow][q*4..+3]; coalesced global reads
  for (int i = tid; i < 2048; i += 256) {
    int q = i & 63, rr = i >> 6;
    int grow = (rr >> 3) * 256 + jb + (rr & 7);
    wq4[q * 32 + rr] = *(const float4*)(Whh + (size_t)grow * H + q * 4);
  }

  float cc = 0.f, s1 = 0.f, s2 = 0.f;
  if (tid < 8 && !first) cc = cstate[grp * 256 + jb + tid];

  float pv = 0.f;
  if (kc == 0) {
    int tc0 = dir ? (CHUNK - 1) : 0;
    pv = pbase[((size_t)tc0 * BB + b) * G4H + row];
  }
  __syncthreads();

  for (int step = 0; step < CHUNK; ++step) {
    int abs = ebase + step;

    // acquire h_{abs-1}
    if (abs == 0) {
      hlds[tid] = 0.f;
    } else {
      ull* src = hx2 + (size_t)((abs - 1) & 1) * 8192 + grp * 256 + tid;
      ull wd = __hip_atomic_load(src, __ATOMIC_RELAXED, __HIP_MEMORY_SCOPE_AGENT);
      while ((int)(wd >> 32) < abs) {
        __builtin_amdgcn_s_sleep(1);
        wd = __hip_atomic_load(src, __ATOMIC_RELAXED, __HIP_MEMORY_SCOPE_AGENT);
      }
      hlds[tid] = __uint_as_float((unsigned)wd);
    }
    __syncthreads();                               // B_h: h ready

    float acc = (kc == 0) ? pv : 0.f;
    const float4* hq = ((const float4*)hlds) + kc * 8;
    const float4* wp = wq4 + kc * 8 * 32 + r;
#pragma unroll
    for (int i = 0; i < 8; ++i) {
      float4 hv = hq[i];                           // wave: 2 addrs -> free broadcast
      float4 wv = wp[i * 32];                      // lanes contiguous -> conflict-free
      acc += wv.x * hv.x + wv.y * hv.y + wv.z * hv.z + wv.w * hv.w;
    }
    pbuf[kc * 32 + r] = acc;
    __syncthreads();                               // B1: partials ready

    int tc = dir ? (CHUNK - 1 - step) : step;
    int t = (dir ? t0b : t0f) + tc;
    if (tid < 64) {                                // wave 0: gate math + publish
      float rs = 0.f;
      if (tid < 32) {
#pragma unroll
        for (int k2i = 0; k2i < 8; ++k2i) rs += pbuf[k2i * 32 + tid];
      }
      int base = tid & 7;
      float gi = __shfl(rs, base, 64);
      float gf = __shfl(rs, base + 8, 64);
      float gg = __shfl(rs, base + 16, 64);
      float go = __shfl(rs, base + 24, 64);
      if (tid < 8) {
        float ig = 1.f / (1.f + expf(-gi));
        float fg = 1.f / (1.f + expf(-gf));
        float gz = tanhf(gg);
        float og = 1.f / (1.f + expf(-go));
        cc = fg * cc + ig * gz;
        float h = og * tanhf(cc);
        s1 += h; s2 += h * h;
        ull wd = ((ull)(unsigned)(abs + 1) << 32) | (ull)__float_as_uint(h);
        __hip_atomic_store(hx2 + (size_t)(abs & 1) * 8192 + grp * 256 + jb + tid, wd,
                           __ATOMIC_RELAXED, __HIP_MEMORY_SCOPE_AGENT);
        hbuf[((size_t)t * BB + b) * 512 + dir * 256 + jb + tid] = h;
      }
    }
    if (kc == 0 && step + 1 < CHUNK) {             // prefetch next proj
      int tcn = dir ? (CHUNK - 2 - step) : (step + 1);
      pv = pbase[((size_t)tcn * BB + b) * G4H + row];
    }
    // no bottom barrier: next iteration's poll + B_h provides separation
  }

  if (tid < 8) {
    cstate[grp * 256 + jb + tid] = cc;
    atomicAdd(&stats[dir * 256 + jb + tid], s1);
    atomicAdd(&stats[512 + dir * 256 + jb + tid], s2);
  }
}

// ---------------- K3: fold BN into linear ----------------
__global__ __launch_bounds__(512) void k3_prep(
    const float* __restrict__ stats, const float* __restrict__ gamma,
    const float* __restrict__ beta, const float* __restrict__ Wlin,
    const float* __restrict__ blin, float* __restrict__ w2, float* __restrict__ b2) {
  __shared__ float r0[512], r1[512];
  int ch = threadIdx.x;
  float mean = stats[ch] * (1.f / 32768.f);
  float var  = stats[512 + ch] * (1.f / 32768.f) - mean * mean;
  float sc = gamma[ch] * rsqrtf(var + 1e-5f);
  float w0 = Wlin[ch], w1 = Wlin[512 + ch];
  w2[ch] = w0 * sc; w2[512 + ch] = w1 * sc;
  float tt = beta[ch] - mean * sc;
  r0[ch] = w0 * tt; r1[ch] = w1 * tt;
  __syncthreads();
  for (int off = 256; off > 0; off >>= 1) {
    if (ch < off) { r0[ch] += r0[ch + off]; r1[ch] += r1[ch + off]; }
    __syncthreads();
  }
  if (ch == 0) { b2[0] = blin[0] + r0[0]; b2[1] = blin[1] + r1[0]; }
}

// ---------------- K4: posterior + gumbel hard sample; one wave per (b,t) ----------------
__global__ __launch_bounds__(256) void k4_post(
    const float* __restrict__ hbuf, const float* __restrict__ w2,
    const float* __restrict__ b2, const float* __restrict__ u,
    const float* __restrict__ e, float* __restrict__ post,
    float* __restrict__ samp) {
  int wid = (blockIdx.x * 256 + threadIdx.x) >> 6;
  int lane = threadIdx.x & 63;
  int b = wid >> 11, t = wid & 2047;
  const float* hr = hbuf + ((size_t)t * BB + b) * 512;
  int c0 = lane * 8;
  float d0 = 0.f, d1 = 0.f;
#pragma unroll
  for (int q = 0; q < 8; q++) {
    float hv = hr[c0 + q];
    d0 += w2[c0 + q] * hv;
    d1 += w2[512 + c0 + q] * hv;
  }
#pragma unroll
  for (int off = 32; off > 0; off >>= 1) {
    d0 += __shfl_xor(d0, off, 64);
    d1 += __shfl_xor(d1, off, 64);
  }
  if (lane == 0) {
    float z0 = (d0 + b2[0]) * 0.1f, z1 = (d1 + b2[1]) * 0.1f;
    float m = fmaxf(z0, z1);
    float e0 = expf(z0 - m), e1 = expf(z1 - m);
    float inv = 1.f / (e0 + e1);
    float p0 = e0 * inv, p1 = e1 * inv;
    size_t o = (size_t)b * TT + t;
    post[o * 2] = p0; post[o * 2 + 1] = p1;
    float u0 = u[o * 2], u1 = u[o * 2 + 1];
    float g0 = -logf(-logf(u0 + 1e-20f) + 1e-20f);
    float g1 = -logf(-logf(u1 + 1e-20f) + 1e-20f);
    float a0 = logf(p0) + g0, a1 = logf(p1) + g1;
    samp[o] = (a1 > a0) ? e[o] : 0.f;  // strict >: np.argmax tie -> class 0
  }
}

// ---------------- K5: 3x median-of-5 (reflect pad), one WG per b ----------------
#define MSWAP(a, b) { float lo_ = fminf(a, b); b = fmaxf(a, b); a = lo_; }
__global__ __launch_bounds__(256) void k5_median(
    const float* __restrict__ samp, float* __restrict__ mask) {
  __shared__ float buf[2][TT];
  int b = blockIdx.x, tid = threadIdx.x;
  for (int i = tid; i < TT; i += 256) buf[0][i] = samp[(size_t)b * TT + i];
  __syncthreads();
  int src = 0;
  for (int pass = 0; pass < 3; ++pass) {
    for (int i = tid; i < TT; i += 256) {
      float v0, v1, v2, v3, v4;
      {
        int i0 = i - 2; i0 = i0 < 0 ? -i0 : i0;
        int i1 = i - 1; i1 = i1 < 0 ? -i1 : i1;
        int i3 = i + 1; i3 = i3 > TT - 1 ? 2 * (TT - 1) - i3 : i3;
        int i4 = i + 2; i4 = i4 > TT - 1 ? 2 * (TT - 1) - i4 : i4;
        v0 = buf[src][i0]; v1 = buf[src][i1]; v2 = buf[src][i];
        v3 = buf[src][i3]; v4 = buf[src][i4];
      }
      MSWAP(v0, v1); MSWAP(v3, v4); MSWAP(v2, v4); MSWAP(v2, v3);
      MSWAP(v1, v4); MSWAP(v0, v3); MSWAP(v0, v2); MSWAP(v1, v3);
      MSWAP(v1, v2);
      buf[1 - src][i] = v2;
    }
    __syncthreads();
    src = 1 - src;
  }
  for (int i = tid; i < TT; i += 256) mask[(size_t)b * TT + i] = buf[src][i];
}

extern "C" void kernel_launch(void* const* d_in, const int* in_sizes, int n_in,
                              void* d_out, int out_size, void* d_ws, size_t ws_size,
                              hipStream_t stream) {
  const float* x    = (const float*)d_in[0];
  const float* e    = (const float*)d_in[1];
  const float* u    = (const float*)d_in[2];
  const float* WihF = (const float*)d_in[3];
  const float* WhhF = (const float*)d_in[4];
  const float* bihF = (const float*)d_in[5];
  const float* bhhF = (const float*)d_in[6];
  const float* WihB = (const float*)d_in[7];
  const float* WhhB = (const float*)d_in[8];
  const float* bihB = (const float*)d_in[9];
  const float* bhhB = (const float*)d_in[10];
  const float* gamma= (const float*)d_in[11];
  const float* beta = (const float*)d_in[12];
  const float* Wlin = (const float*)d_in[13];
  const float* blin = (const float*)d_in[14];

  float* ws = (float*)d_ws;
  float* projF  = ws + OFF_PROJF;
  float* projB  = ws + OFF_PROJB;
  float* hbuf   = ws + OFF_HBUF;
  float* stats  = ws + OFF_STATS;
  float* cstate = ws + OFF_CSTATE;
  ull*   hx2    = (ull*)(ws + OFF_HX);
  float* w2     = ws + OFF_W2;
  float* b2     = ws + OFF_B2;
  float* samp   = ws + OFF_SAMP;

  float* post = (float*)d_out;
  float* mask = (float*)d_out + (size_t)BB * TT * 2;

  hipLaunchKernelGGL(k0_init, dim3(128), dim3(256), 0, stream, stats, (int*)hx2);
  for (int p = 0; p < NPH; ++p) {
    int t0f = p * CHUNK;
    int t0b = (NPH - 1 - p) * CHUNK;
    hipLaunchKernelGGL(k1_proj, dim3(CHUNK / 64, 16, 32), dim3(256), 0, stream,
                       x, WihF, bihF, bhhF, WihB, bihB, bhhB, projF, projB, t0f, t0b);
    hipLaunchKernelGGL(k2_rec, dim3(1024), dim3(256), 0, stream,
                       WhhF, WhhB, projF, projB, hbuf, hx2,
                       cstate, stats, t0f, t0b, p * CHUNK, p == 0 ? 1 : 0);
  }
  hipLaunchKernelGGL(k3_prep, dim3(1), dim3(512), 0, stream,
                     stats, gamma, beta, Wlin, blin, w2, b2);
  hipLaunchKernelGGL(k4_post, dim3(8192), dim3(256), 0, stream,
                     hbuf, w2, b2, u, e, post, samp);
  hipLaunchKernelGGL(k5_median, dim3(16), dim3(256), 0, stream, samp, mask);
}

// Round 9
// 4416.908 us; speedup vs baseline: 2.8160x; 1.8053x over previous
//
#include <hip/hip_runtime.h>
#include <math.h>

#define H    256
#define G4H  1024
#define CIN  512
#define BB   16
#define TT   2048
#define CHUNK 256
#define NPH  8   // TT/CHUNK

typedef unsigned long long ull;

// ---- workspace layout (in floats) ----
#define OFF_WQ      ((size_t)0)                        // 131072 float4 = 524288 floats
#define OFF_PROJF   ((size_t)524288)                   // 4194304
#define OFF_PROJB   ((size_t)4718592)                  // 4194304
#define OFF_HBUF    ((size_t)8912896)                  // 16777216
#define OFF_STATS   ((size_t)25690112)                 // 1024
#define OFF_CSTATE  ((size_t)25691136)                 // 8192
#define OFF_HX      ((size_t)25699328)                 // 16384 ull = 32768 floats (8B aligned)
#define OFF_W2      ((size_t)25732096)                 // 1024
#define OFF_B2      ((size_t)25733120)                 // 16
#define OFF_SAMP    ((size_t)25733136)                 // 32768

#define REP16(X) X(0) X(1) X(2) X(3) X(4) X(5) X(6) X(7) X(8) X(9) X(10) X(11) \
  X(12) X(13) X(14) X(15)

// ---------------- K0: repack Whh; zero stats + hx tag words ----------------
// wq float4 idx = (dir*4+kq)*16384 + q*1024 + gate*256 + s*32 + jl
// value = Whh_dir[gate*256 + s*32 + jl][kq*64 + q*4 .. +3]
__global__ __launch_bounds__(256) void k0_init(
    const float* __restrict__ WhhF, const float* __restrict__ WhhB,
    float4* __restrict__ wq, float* __restrict__ stats, int* __restrict__ hxw) {
  int idx = blockIdx.x * 256 + threadIdx.x;
  if (idx < 131072) {
    int jl = idx & 31, s = (idx >> 5) & 7, gate = (idx >> 8) & 3;
    int q = (idx >> 10) & 15, kq = (idx >> 14) & 3, dir = idx >> 16;
    int row = gate * 256 + s * 32 + jl;
    int col = kq * 64 + q * 4;
    const float* W = (dir ? WhhB : WhhF) + (size_t)row * H + col;
    wq[idx] = make_float4(W[0], W[1], W[2], W[3]);
  }
  if (idx < 1024) stats[idx] = 0.f;
  if (idx < 32768) hxw[idx] = 0;   // tags=0 < any target>=1
}

// ---------------- K1: proj[tc][b][g] = sum_c x[b][c][t] * Wih[g][c] + bih[g]+bhh[g] ----------------
__global__ __launch_bounds__(256) void k1_proj(
    const float* __restrict__ x,
    const float* __restrict__ WihF, const float* __restrict__ bihF, const float* __restrict__ bhhF,
    const float* __restrict__ WihB, const float* __restrict__ bihB, const float* __restrict__ bhhB,
    float* __restrict__ projF, float* __restrict__ projB, int t0f, int t0b) {
  __shared__ __align__(16) float Xs[16][68];
  __shared__ __align__(16) float Ws[16][68];
  int tid = threadIdx.x;
  int b = blockIdx.z & 15, dir = blockIdx.z >> 4;
  const float* Wih = dir ? WihB : WihF;
  const float* bih = dir ? bihB : bihF;
  const float* bhh = dir ? bhhB : bhhF;
  float* proj = dir ? projB : projF;
  int tbase = (dir ? t0b : t0f) + blockIdx.x * 64;
  int gbase = blockIdx.y * 64;
  int tx = tid & 15, ty = tid >> 4;
  float acc[4][4];
#pragma unroll
  for (int i = 0; i < 4; i++)
#pragma unroll
    for (int j = 0; j < 4; j++) acc[i][j] = 0.f;

  int lt = tid & 63, lk = tid >> 6;
  int wk = tid & 15, wg = tid >> 4;
  const float* xb = x + (size_t)b * CIN * TT;

  for (int c0 = 0; c0 < CIN; c0 += 16) {
    __syncthreads();
#pragma unroll
    for (int q = 0; q < 4; q++)
      Xs[lk + 4 * q][lt] = xb[(size_t)(c0 + lk + 4 * q) * TT + tbase + lt];
#pragma unroll
    for (int q = 0; q < 4; q++)
      Ws[wk][wg + 16 * q] = Wih[(size_t)(gbase + wg + 16 * q) * CIN + c0 + wk];
    __syncthreads();
#pragma unroll
    for (int kk = 0; kk < 16; kk++) {
      float4 av = *(const float4*)&Xs[kk][tx * 4];
      float4 bv = *(const float4*)&Ws[kk][ty * 4];
      acc[0][0] += av.x * bv.x; acc[0][1] += av.x * bv.y; acc[0][2] += av.x * bv.z; acc[0][3] += av.x * bv.w;
      acc[1][0] += av.y * bv.x; acc[1][1] += av.y * bv.y; acc[1][2] += av.y * bv.z; acc[1][3] += av.y * bv.w;
      acc[2][0] += av.z * bv.x; acc[2][1] += av.z * bv.y; acc[2][2] += av.z * bv.z; acc[2][3] += av.z * bv.w;
      acc[3][0] += av.w * bv.x; acc[3][1] += av.w * bv.y; acc[3][2] += av.w * bv.z; acc[3][3] += av.w * bv.w;
    }
  }
  int g0 = gbase + ty * 4;
  float bias0 = bih[g0 + 0] + bhh[g0 + 0];
  float bias1 = bih[g0 + 1] + bhh[g0 + 1];
  float bias2 = bih[g0 + 2] + bhh[g0 + 2];
  float bias3 = bih[g0 + 3] + bhh[g0 + 3];
#pragma unroll
  for (int i = 0; i < 4; i++) {
    int tc = blockIdx.x * 64 + tx * 4 + i;
    float4 st = make_float4(acc[i][0] + bias0, acc[i][1] + bias1,
                            acc[i][2] + bias2, acc[i][3] + bias3);
    *(float4*)(proj + ((size_t)tc * BB + b) * G4H + g0) = st;
  }
}

// ---------------- K2: LSTM recurrence (round-6 structure + single-trip tagged exchange) ----
// 8 sibling WGs x 512 thr per (dir,b). Thread: jl=tid&31, gate=(tid>>5)&3, kq=tid>>7.
// 16 float4 weights per thread, asm-pinned (lands in AGPRs - verified r6: FETCH shows no re-read).
// Exchange: hx2[parity][chain][j] = (tag=abs+1)<<32 | h_bits (one 8B relaxed agent atomic).
// Consumers poll the data word directly: no drain, no epoch, no second trip. Tight spin (1 WG/CU).
__global__ __launch_bounds__(512, 1) void k2_rec(
    const float4* __restrict__ wq, const float* __restrict__ projF,
    const float* __restrict__ projB, float* __restrict__ hbuf,
    ull* __restrict__ hx2, float* __restrict__ cstate,
    float* __restrict__ stats, int t0f, int t0b, int first, int ebase) {
  __shared__ __align__(16) float h_lds[256];
  __shared__ float pbuf[512];
  const int tid = threadIdx.x;
  const int l = tid & 63, w = tid >> 6;
  const int jl = tid & 31, gate = (tid >> 5) & 3, kq = tid >> 7;
  const int bx = blockIdx.x;
  const int grp = bx & 31, s = bx >> 5;     // 8 siblings: {g, g+32, ..., g+224}
  const int dir = grp >> 4, b = grp & 15;
  const int row = gate * 256 + s * 32 + jl; // gate row [0,1024)

  const float4* wbase = wq + (size_t)(dir * 4 + kq) * 16384 + gate * 256 + s * 32 + jl;
#define WDECL(i) float wx##i, wy##i, wz##i, ww##i; \
  { float4 t_ = wbase[(size_t)(i) * 1024]; \
    wx##i = t_.x; wy##i = t_.y; wz##i = t_.z; ww##i = t_.w; } \
  asm volatile("" : "+v"(wx##i), "+v"(wy##i), "+v"(wz##i), "+v"(ww##i));
  REP16(WDECL)
#undef WDECL

  float c = 0.f, s1 = 0.f, s2 = 0.f;
  if (w == 0 && l < 32 && !first) c = cstate[grp * 256 + s * 32 + l];

  const float* pbase = dir ? projB : projF;
  float pv = 0.f;
  if (kq == 0) {
    int tc0 = dir ? (CHUNK - 1) : 0;
    pv = pbase[((size_t)tc0 * BB + b) * G4H + row];
  }

  for (int step = 0; step < CHUNK; ++step) {
    int abs = ebase + step;

    // acquire h_{abs-1}: poll tagged words directly (tag >= abs)
    if (tid < 256) {
      if (abs == 0) {
        h_lds[tid] = 0.f;
      } else {
        ull* src = hx2 + (size_t)((abs - 1) & 1) * 8192 + grp * 256 + tid;
        ull wd = __hip_atomic_load(src, __ATOMIC_RELAXED, __HIP_MEMORY_SCOPE_AGENT);
        while ((int)(wd >> 32) < abs)
          wd = __hip_atomic_load(src, __ATOMIC_RELAXED, __HIP_MEMORY_SCOPE_AGENT);
        h_lds[tid] = __uint_as_float((unsigned)wd);
      }
    }
    __syncthreads();                          // A: h ready

    float acc = (kq == 0) ? pv : 0.f;
    const float4* h4p = ((const float4*)h_lds) + (kq << 4);
#define WFMA(i) { float4 hv = h4p[i]; \
    acc += wx##i * hv.x + wy##i * hv.y + wz##i * hv.z + ww##i * hv.w; }
    REP16(WFMA)
#undef WFMA
    pbuf[tid] = acc;
    __syncthreads();                          // B: partials ready (h_lds reads done)

    if (w == 0 && l < 32) {
      float gi = pbuf[l]       + pbuf[128 + l] + pbuf[256 + l] + pbuf[384 + l];
      float gf = pbuf[32 + l]  + pbuf[160 + l] + pbuf[288 + l] + pbuf[416 + l];
      float gg = pbuf[64 + l]  + pbuf[192 + l] + pbuf[320 + l] + pbuf[448 + l];
      float go = pbuf[96 + l]  + pbuf[224 + l] + pbuf[352 + l] + pbuf[480 + l];
      float ig = 1.f / (1.f + expf(-gi));
      float fg = 1.f / (1.f + expf(-gf));
      float gz = tanhf(gg);
      float og = 1.f / (1.f + expf(-go));
      c = fg * c + ig * gz;
      float h = og * tanhf(c);
      s1 += h; s2 += h * h;
      int j = s * 32 + l;
      ull wd = ((ull)(unsigned)(abs + 1) << 32) | (ull)__float_as_uint(h);
      __hip_atomic_store(hx2 + (size_t)(abs & 1) * 8192 + grp * 256 + j, wd,
                         __ATOMIC_RELAXED, __HIP_MEMORY_SCOPE_AGENT);
      // streaming store off the critical path (after publish)
      int tc = dir ? (CHUNK - 1 - step) : step;
      int t = (dir ? t0b : t0f) + tc;
      hbuf[((size_t)t * BB + b) * 512 + dir * 256 + j] = h;
    }
    if (kq == 0 && step + 1 < CHUNK) {        // prefetch next proj
      int tcn = dir ? (CHUNK - 2 - step) : (step + 1);
      pv = pbase[((size_t)tcn * BB + b) * G4H + row];
    }
    // no bottom barrier: next poll + barrier A separates steps
  }

  if (w == 0 && l < 32) {
    cstate[grp * 256 + s * 32 + l] = c;
    atomicAdd(&stats[dir * 256 + s * 32 + l], s1);
    atomicAdd(&stats[512 + dir * 256 + s * 32 + l], s2);
  }
}

// ---------------- K3: fold BN into linear ----------------
__global__ __launch_bounds__(512) void k3_prep(
    const float* __restrict__ stats, const float* __restrict__ gamma,
    const float* __restrict__ beta, const float* __restrict__ Wlin,
    const float* __restrict__ blin, float* __restrict__ w2, float* __restrict__ b2) {
  __shared__ float r0[512], r1[512];
  int ch = threadIdx.x;
  float mean = stats[ch] * (1.f / 32768.f);
  float var  = stats[512 + ch] * (1.f / 32768.f) - mean * mean;
  float sc = gamma[ch] * rsqrtf(var + 1e-5f);
  float w0 = Wlin[ch], w1 = Wlin[512 + ch];
  w2[ch] = w0 * sc; w2[512 + ch] = w1 * sc;
  float tt = beta[ch] - mean * sc;
  r0[ch] = w0 * tt; r1[ch] = w1 * tt;
  __syncthreads();
  for (int off = 256; off > 0; off >>= 1) {
    if (ch < off) { r0[ch] += r0[ch + off]; r1[ch] += r1[ch + off]; }
    __syncthreads();
  }
  if (ch == 0) { b2[0] = blin[0] + r0[0]; b2[1] = blin[1] + r1[0]; }
}

// ---------------- K4: posterior + gumbel hard sample; one wave per (b,t) ----------------
__global__ __launch_bounds__(256) void k4_post(
    const float* __restrict__ hbuf, const float* __restrict__ w2,
    const float* __restrict__ b2, const float* __restrict__ u,
    const float* __restrict__ e, float* __restrict__ post,
    float* __restrict__ samp) {
  int wid = (blockIdx.x * 256 + threadIdx.x) >> 6;
  int lane = threadIdx.x & 63;
  int b = wid >> 11, t = wid & 2047;
  const float* hr = hbuf + ((size_t)t * BB + b) * 512;
  int c0 = lane * 8;
  float d0 = 0.f, d1 = 0.f;
#pragma unroll
  for (int q = 0; q < 8; q++) {
    float hv = hr[c0 + q];
    d0 += w2[c0 + q] * hv;
    d1 += w2[512 + c0 + q] * hv;
  }
#pragma unroll
  for (int off = 32; off > 0; off >>= 1) {
    d0 += __shfl_xor(d0, off, 64);
    d1 += __shfl_xor(d1, off, 64);
  }
  if (lane == 0) {
    float z0 = (d0 + b2[0]) * 0.1f, z1 = (d1 + b2[1]) * 0.1f;
    float m = fmaxf(z0, z1);
    float e0 = expf(z0 - m), e1 = expf(z1 - m);
    float inv = 1.f / (e0 + e1);
    float p0 = e0 * inv, p1 = e1 * inv;
    size_t o = (size_t)b * TT + t;
    post[o * 2] = p0; post[o * 2 + 1] = p1;
    float u0 = u[o * 2], u1 = u[o * 2 + 1];
    float g0 = -logf(-logf(u0 + 1e-20f) + 1e-20f);
    float g1 = -logf(-logf(u1 + 1e-20f) + 1e-20f);
    float a0 = logf(p0) + g0, a1 = logf(p1) + g1;
    samp[o] = (a1 > a0) ? e[o] : 0.f;  // strict >: np.argmax tie -> class 0
  }
}

// ---------------- K5: 3x median-of-5 (reflect pad), one WG per b ----------------
#define MSWAP(a, b) { float lo_ = fminf(a, b); b = fmaxf(a, b); a = lo_; }
__global__ __launch_bounds__(256) void k5_median(
    const float* __restrict__ samp, float* __restrict__ mask) {
  __shared__ float buf[2][TT];
  int b = blockIdx.x, tid = threadIdx.x;
  for (int i = tid; i < TT; i += 256) buf[0][i] = samp[(size_t)b * TT + i];
  __syncthreads();
  int src = 0;
  for (int pass = 0; pass < 3; ++pass) {
    for (int i = tid; i < TT; i += 256) {
      float v0, v1, v2, v3, v4;
      {
        int i0 = i - 2; i0 = i0 < 0 ? -i0 : i0;
        int i1 = i - 1; i1 = i1 < 0 ? -i1 : i1;
        int i3 = i + 1; i3 = i3 > TT - 1 ? 2 * (TT - 1) - i3 : i3;
        int i4 = i + 2; i4 = i4 > TT - 1 ? 2 * (TT - 1) - i4 : i4;
        v0 = buf[src][i0]; v1 = buf[src][i1]; v2 = buf[src][i];
        v3 = buf[src][i3]; v4 = buf[src][i4];
      }
      MSWAP(v0, v1); MSWAP(v3, v4); MSWAP(v2, v4); MSWAP(v2, v3);
      MSWAP(v1, v4); MSWAP(v0, v3); MSWAP(v0, v2); MSWAP(v1, v3);
      MSWAP(v1, v2);
      buf[1 - src][i] = v2;
    }
    __syncthreads();
    src = 1 - src;
  }
  for (int i = tid; i < TT; i += 256) mask[(size_t)b * TT + i] = buf[src][i];
}

extern "C" void kernel_launch(void* const* d_in, const int* in_sizes, int n_in,
                              void* d_out, int out_size, void* d_ws, size_t ws_size,
                              hipStream_t stream) {
  const float* x    = (const float*)d_in[0];
  const float* e    = (const float*)d_in[1];
  const float* u    = (const float*)d_in[2];
  const float* WihF = (const float*)d_in[3];
  const float* WhhF = (const float*)d_in[4];
  const float* bihF = (const float*)d_in[5];
  const float* bhhF = (const float*)d_in[6];
  const float* WihB = (const float*)d_in[7];
  const float* WhhB = (const float*)d_in[8];
  const float* bihB = (const float*)d_in[9];
  const float* bhhB = (const float*)d_in[10];
  const float* gamma= (const float*)d_in[11];
  const float* beta = (const float*)d_in[12];
  const float* Wlin = (const float*)d_in[13];
  const float* blin = (const float*)d_in[14];

  float* ws = (float*)d_ws;
  float4* wq    = (float4*)(ws + OFF_WQ);
  float* projF  = ws + OFF_PROJF;
  float* projB  = ws + OFF_PROJB;
  float* hbuf   = ws + OFF_HBUF;
  float* stats  = ws + OFF_STATS;
  float* cstate = ws + OFF_CSTATE;
  ull*   hx2    = (ull*)(ws + OFF_HX);
  float* w2     = ws + OFF_W2;
  float* b2     = ws + OFF_B2;
  float* samp   = ws + OFF_SAMP;

  float* post = (float*)d_out;
  float* mask = (float*)d_out + (size_t)BB * TT * 2;

  hipLaunchKernelGGL(k0_init, dim3(512), dim3(256), 0, stream,
                     WhhF, WhhB, wq, stats, (int*)hx2);
  for (int p = 0; p < NPH; ++p) {
    int t0f = p * CHUNK;
    int t0b = (NPH - 1 - p) * CHUNK;
    hipLaunchKernelGGL(k1_proj, dim3(CHUNK / 64, 16, 32), dim3(256), 0, stream,
                       x, WihF, bihF, bhhF, WihB, bihB, bhhB, projF, projB, t0f, t0b);
    hipLaunchKernelGGL(k2_rec, dim3(256), dim3(512), 0, stream,
                       wq, projF, projB, hbuf, hx2,
                       cstate, stats, t0f, t0b, p == 0 ? 1 : 0, p * CHUNK);
  }
  hipLaunchKernelGGL(k3_prep, dim3(1), dim3(512), 0, stream,
                     stats, gamma, beta, Wlin, blin, w2, b2);
  hipLaunchKernelGGL(k4_post, dim3(8192), dim3(256), 0, stream,
                     hbuf, w2, b2, u, e, post, samp);
  hipLaunchKernelGGL(k5_median, dim3(16), dim3(256), 0, stream, samp, mask);
}